// Round 1
// baseline (93.939 us; speedup 1.0000x reference)
//
#include <hip/hip_runtime.h>
#include <hip/hip_bf16.h>

typedef __attribute__((ext_vector_type(8))) short bf16x8;
typedef __attribute__((ext_vector_type(4))) float f32x4;

#define B_ROWS 8192
#define FDIM 128

// ---------------- Kernel A: normalize rows of z1,z2 -> bf16; compute pos[i] ----------------
__global__ __launch_bounds__(256) void simclr_norm(const float* __restrict__ z1,
                                                   const float* __restrict__ z2,
                                                   __hip_bfloat16* __restrict__ z1n,
                                                   __hip_bfloat16* __restrict__ z2n,
                                                   float* __restrict__ pos) {
    int row  = (blockIdx.x * 256 + threadIdx.x) >> 6;   // one wave per row
    int lane = threadIdx.x & 63;
    int c = lane * 2;
    const float2 v1 = *(const float2*)(z1 + row * FDIM + c);
    const float2 v2 = *(const float2*)(z2 + row * FDIM + c);
    float s1 = v1.x * v1.x + v1.y * v1.y;
    float s2 = v2.x * v2.x + v2.y * v2.y;
    for (int m = 32; m > 0; m >>= 1) { s1 += __shfl_xor(s1, m); s2 += __shfl_xor(s2, m); }
    float inv1 = 1.0f / fmaxf(sqrtf(s1), 1e-12f);
    float inv2 = 1.0f / fmaxf(sqrtf(s2), 1e-12f);
    float a0 = v1.x * inv1, a1 = v1.y * inv1;
    float b0 = v2.x * inv2, b1 = v2.y * inv2;
    z1n[row * FDIM + c]     = __float2bfloat16(a0);
    z1n[row * FDIM + c + 1] = __float2bfloat16(a1);
    z2n[row * FDIM + c]     = __float2bfloat16(b0);
    z2n[row * FDIM + c + 1] = __float2bfloat16(b1);
    float p = a0 * b0 + a1 * b1;
    for (int m = 32; m > 0; m >>= 1) p += __shfl_xor(p, m);
    if (lane == 0) pos[row] = p;
}

// ---------------- Kernel B: S-tile GEMM (bf16 MFMA) + exp + row-sum ----------------
// 128x128 output tile, K=128 fully resident in LDS. 4 waves (2x2), each 64x64.
__global__ __launch_bounds__(256) void simclr_gemm(const __hip_bfloat16* __restrict__ z1n,
                                                   const __hip_bfloat16* __restrict__ z2n,
                                                   float* __restrict__ rs) {
    __shared__ unsigned char smem[65536];   // A tile @0, B tile @32768
    const int tid = threadIdx.x;
    const int rowBase = blockIdx.y * 128;
    const int colBase = blockIdx.x * 128;

    const unsigned short* g1 = (const unsigned short*)z1n;
    const unsigned short* g2 = (const unsigned short*)z2n;

    // Stage both tiles: 8 passes x 256 threads x 16B. XOR-swizzle to kill the
    // 32-way bank conflict of row-major D=128 tiles (byte ^= (row&7)<<4).
#pragma unroll
    for (int p = 0; p < 8; ++p) {
        int e = p * 2048 + tid * 8;        // flat elem idx in 128x128
        int r = e >> 7, c = e & 127;
        int byteOff = r * 256 + ((c * 2) ^ ((r & 7) << 4));
        uint4 va = *(const uint4*)(g1 + (size_t)(rowBase + r) * FDIM + c);
        *(uint4*)(smem + byteOff) = va;
        uint4 vb = *(const uint4*)(g2 + (size_t)(colBase + r) * FDIM + c);
        *(uint4*)(smem + 32768 + byteOff) = vb;
    }
    __syncthreads();

    const int wid = tid >> 6, lane = tid & 63;
    const int wr = (wid >> 1) * 64;   // wave row offset in tile
    const int wc = (wid & 1) * 64;    // wave col offset in tile

    f32x4 acc[4][4] = {};
#pragma unroll
    for (int kk = 0; kk < 4; ++kk) {
        const int kByte = kk * 64 + (lane >> 4) * 16;   // k = kk*32 + (lane>>4)*8, *2B
        bf16x8 a[4], b[4];
#pragma unroll
        for (int m = 0; m < 4; ++m) {
            int r = wr + m * 16 + (lane & 15);
            a[m] = *(const bf16x8*)(smem + r * 256 + (kByte ^ ((r & 7) << 4)));
        }
#pragma unroll
        for (int n = 0; n < 4; ++n) {
            int r = wc + n * 16 + (lane & 15);
            b[n] = *(const bf16x8*)(smem + 32768 + r * 256 + (kByte ^ ((r & 7) << 4)));
        }
#pragma unroll
        for (int m = 0; m < 4; ++m)
#pragma unroll
            for (int n = 0; n < 4; ++n)
                acc[m][n] = __builtin_amdgcn_mfma_f32_16x16x32_bf16(a[m], b[n], acc[m][n], 0, 0, 0);
    }

    // Epilogue: exp + row-sum. C/D map: col=lane&15, row=(lane>>4)*4+reg (m89).
#pragma unroll
    for (int m = 0; m < 4; ++m) {
#pragma unroll
        for (int r = 0; r < 4; ++r) {
            float s = 0.0f;
#pragma unroll
            for (int n = 0; n < 4; ++n) s += __expf(acc[m][n][r]);
            // reduce across the 16 lanes holding different cols of this row
            s += __shfl_xor(s, 1); s += __shfl_xor(s, 2);
            s += __shfl_xor(s, 4); s += __shfl_xor(s, 8);
            if ((lane & 15) == 0) {
                int gi = rowBase + wr + m * 16 + (lane >> 4) * 4 + r;
                atomicAdd(&rs[gi], s);
            }
        }
    }
}

// ---------------- Kernel C: loss = mean(log(rowsum) - pos) ----------------
__global__ __launch_bounds__(1024) void simclr_finish(const float* __restrict__ rs,
                                                      const float* __restrict__ pos,
                                                      float* __restrict__ out) {
    __shared__ float red[16];
    int tid = threadIdx.x;
    float s = 0.0f;
    for (int i = tid; i < B_ROWS; i += 1024) s += logf(rs[i]) - pos[i];
    for (int m = 32; m > 0; m >>= 1) s += __shfl_xor(s, m);
    if ((tid & 63) == 0) red[tid >> 6] = s;
    __syncthreads();
    if (tid < 16) {
        float v = red[tid];
        for (int m = 8; m > 0; m >>= 1) v += __shfl_xor(v, m);
        if (tid == 0) *out = v / (float)B_ROWS;
    }
}

extern "C" void kernel_launch(void* const* d_in, const int* in_sizes, int n_in,
                              void* d_out, int out_size, void* d_ws, size_t ws_size,
                              hipStream_t stream) {
    const float* z1 = (const float*)d_in[0];
    const float* z2 = (const float*)d_in[1];
    float* out = (float*)d_out;
    char* ws = (char*)d_ws;

    __hip_bfloat16* z1n = (__hip_bfloat16*)ws;                       // 2 MB
    __hip_bfloat16* z2n = (__hip_bfloat16*)(ws + 2097152);           // 2 MB
    float* pos          = (float*)(ws + 4194304);                    // 32 KB
    float* rs           = (float*)(ws + 4194304 + 32768);            // 32 KB

    hipMemsetAsync(rs, 0, B_ROWS * sizeof(float), stream);
    simclr_norm<<<B_ROWS / 4, 256, 0, stream>>>(z1, z2, z1n, z2n, pos);
    simclr_gemm<<<dim3(64, 64), 256, 0, stream>>>(z1n, z2n, rs);
    simclr_finish<<<1, 1024, 0, stream>>>(rs, pos, out);
}

// Round 2
// 42.626 us; speedup vs baseline: 2.2038x; 2.2038x over previous
//
#include <hip/hip_runtime.h>
#include <hip/hip_bf16.h>

typedef __attribute__((ext_vector_type(8))) short bf16x8;
typedef __attribute__((ext_vector_type(4))) float f32x4;

#define B_ROWS 8192
#define FDIM 128
#define NT 8            // col-tiles per block
#define BN 128          // cols per tile
#define CHUNK (NT*BN)   // 1024 cols per block

// global->LDS direct, 16B/lane, wave-uniform LDS base + lane*16 (HW rule).
#define GLOAD_LDS(gp, lp) __builtin_amdgcn_global_load_lds( \
    (const __attribute__((address_space(1))) unsigned*)(gp), \
    (__attribute__((address_space(3))) unsigned*)(lp), 16, 0, 0)

// ---------------- Kernel A: normalize rows of z1,z2 -> bf16; compute pos[i] ----------------
__global__ __launch_bounds__(256) void simclr_norm(const float* __restrict__ z1,
                                                   const float* __restrict__ z2,
                                                   __hip_bfloat16* __restrict__ z1n,
                                                   __hip_bfloat16* __restrict__ z2n,
                                                   float* __restrict__ pos) {
    int row  = (blockIdx.x * 256 + threadIdx.x) >> 6;   // one wave per row
    int lane = threadIdx.x & 63;
    int c = lane * 2;
    const float2 v1 = *(const float2*)(z1 + row * FDIM + c);
    const float2 v2 = *(const float2*)(z2 + row * FDIM + c);
    float s1 = v1.x * v1.x + v1.y * v1.y;
    float s2 = v2.x * v2.x + v2.y * v2.y;
    for (int m = 32; m > 0; m >>= 1) { s1 += __shfl_xor(s1, m); s2 += __shfl_xor(s2, m); }
    float inv1 = 1.0f / fmaxf(sqrtf(s1), 1e-12f);
    float inv2 = 1.0f / fmaxf(sqrtf(s2), 1e-12f);
    float a0 = v1.x * inv1, a1 = v1.y * inv1;
    float b0 = v2.x * inv2, b1 = v2.y * inv2;
    z1n[row * FDIM + c]     = __float2bfloat16(a0);
    z1n[row * FDIM + c + 1] = __float2bfloat16(a1);
    z2n[row * FDIM + c]     = __float2bfloat16(b0);
    z2n[row * FDIM + c + 1] = __float2bfloat16(b1);
    float p = a0 * b0 + a1 * b1;
    for (int m = 32; m > 0; m >>= 1) p += __shfl_xor(p, m);
    if (lane == 0) pos[row] = p;
}

// ---------------- Kernel B: persistent row-panel GEMM + exp + row-sum ----------------
// Block = 256 rows x 1024 cols; 8 waves (4 waveM x 2 waveN), each 64x64 per tile.
// A (256x128) in registers; B tile (128x128) double-buffered in LDS via
// global_load_lds with pre-swizzled source (XOR slot ^ (row&7)).
__global__ __launch_bounds__(512, 2) void simclr_gemm(const __hip_bfloat16* __restrict__ z1n,
                                                      const __hip_bfloat16* __restrict__ z2n,
                                                      float* __restrict__ rs) {
    __shared__ unsigned char smem[65536];   // two 32KB B buffers
    const int tid = threadIdx.x;
    const int wid = tid >> 6, lane = tid & 63;
    const int lq = lane >> 4, lr = lane & 15;
    const int rowBase = blockIdx.y * 256;
    const int colBase = blockIdx.x * CHUNK;
    const int waveM = wid >> 1, waveN = wid & 1;

    const unsigned short* g1 = (const unsigned short*)z1n;
    const unsigned short* g2 = (const unsigned short*)z2n;

    // stage tile 0 into buf0: wave w stages B-rows [w*16, w*16+16)
#pragma unroll
    for (int j = 0; j < 4; ++j) {
        int rl = wid * 16 + j * 4 + lq;
        const unsigned short* gp = g2 + (size_t)(colBase + rl) * FDIM + (lr ^ (rl & 7)) * 8;
        GLOAD_LDS(gp, smem + wid * 4096 + j * 1024);
    }

    // A fragments -> registers (once)
    bf16x8 a[4][4];
#pragma unroll
    for (int m = 0; m < 4; ++m) {
        int rA = rowBase + waveM * 64 + m * 16 + lr;
        const unsigned short* rp = g1 + (size_t)rA * FDIM + lq * 8;
#pragma unroll
        for (int kk = 0; kk < 4; ++kk)
            a[m][kk] = *(const bf16x8*)(rp + kk * 32);
    }

    float rowsum[4][4] = {};

    for (int t = 0; t < NT; ++t) {
        __syncthreads();                       // drains vmcnt (stage t) + lgkm (reads t-1)
        const int cur = (t & 1) * 32768;
        if (t + 1 < NT) {
            const int colT = colBase + (t + 1) * BN;
            const int nxt = ((t + 1) & 1) * 32768;
#pragma unroll
            for (int j = 0; j < 4; ++j) {
                int rl = wid * 16 + j * 4 + lq;
                const unsigned short* gp = g2 + (size_t)(colT + rl) * FDIM + (lr ^ (rl & 7)) * 8;
                GLOAD_LDS(gp, smem + nxt + wid * 4096 + j * 1024);
            }
        }
        f32x4 acc[4][4] = {};
#pragma unroll
        for (int kk = 0; kk < 4; ++kk) {
            bf16x8 b[4];
            const int kByte = kk * 64 + lq * 16;
#pragma unroll
            for (int n = 0; n < 4; ++n) {
                int rB = waveN * 64 + n * 16 + lr;
                b[n] = *(const bf16x8*)(smem + cur + rB * 256 + (kByte ^ ((rB & 7) << 4)));
            }
#pragma unroll
            for (int m = 0; m < 4; ++m)
#pragma unroll
                for (int n = 0; n < 4; ++n)
                    acc[m][n] = __builtin_amdgcn_mfma_f32_16x16x32_bf16(a[m][kk], b[n], acc[m][n], 0, 0, 0);
        }
        // fuse exp + row-accumulate (rows: (lane>>4)*4 + r; cols: lane&15)
#pragma unroll
        for (int m = 0; m < 4; ++m)
#pragma unroll
            for (int r = 0; r < 4; ++r)
                rowsum[m][r] += __expf(acc[m][0][r]) + __expf(acc[m][1][r]) +
                                __expf(acc[m][2][r]) + __expf(acc[m][3][r]);
    }

    // final: reduce across the 16 col-lanes, one atomic per row per wave
#pragma unroll
    for (int m = 0; m < 4; ++m)
#pragma unroll
        for (int r = 0; r < 4; ++r) {
            float s = rowsum[m][r];
            s += __shfl_xor(s, 1); s += __shfl_xor(s, 2);
            s += __shfl_xor(s, 4); s += __shfl_xor(s, 8);
            if (lr == 0)
                atomicAdd(&rs[rowBase + waveM * 64 + m * 16 + lq * 4 + r], s);
        }
}

// ---------------- Kernel C: loss = mean(log(rowsum) - pos) ----------------
__global__ __launch_bounds__(1024) void simclr_finish(const float* __restrict__ rs,
                                                      const float* __restrict__ pos,
                                                      float* __restrict__ out) {
    __shared__ float red[16];
    int tid = threadIdx.x;
    float s = 0.0f;
    for (int i = tid; i < B_ROWS; i += 1024) s += logf(rs[i]) - pos[i];
    for (int m = 32; m > 0; m >>= 1) s += __shfl_xor(s, m);
    if ((tid & 63) == 0) red[tid >> 6] = s;
    __syncthreads();
    if (tid < 16) {
        float v = red[tid];
        for (int m = 8; m > 0; m >>= 1) v += __shfl_xor(v, m);
        if (tid == 0) *out = v / (float)B_ROWS;
    }
}

extern "C" void kernel_launch(void* const* d_in, const int* in_sizes, int n_in,
                              void* d_out, int out_size, void* d_ws, size_t ws_size,
                              hipStream_t stream) {
    const float* z1 = (const float*)d_in[0];
    const float* z2 = (const float*)d_in[1];
    float* out = (float*)d_out;
    char* ws = (char*)d_ws;

    __hip_bfloat16* z1n = (__hip_bfloat16*)ws;                       // 2 MB
    __hip_bfloat16* z2n = (__hip_bfloat16*)(ws + 2097152);           // 2 MB
    float* pos          = (float*)(ws + 4194304);                    // 32 KB
    float* rs           = (float*)(ws + 4194304 + 32768);            // 32 KB

    hipMemsetAsync(rs, 0, B_ROWS * sizeof(float), stream);
    simclr_norm<<<B_ROWS / 4, 256, 0, stream>>>(z1, z2, z1n, z2n, pos);
    simclr_gemm<<<dim3(NT == 8 ? 8 : 8, 32), 512, 0, stream>>>(z1n, z2n, rs);
    simclr_finish<<<1, 1024, 0, stream>>>(rs, pos, out);
}